// Round 3
// baseline (86.351 us; speedup 1.0000x reference)
//
#include <hip/hip_runtime.h>
#include <hip/hip_bf16.h>
#include <stdint.h>
#include <stddef.h>

typedef __bf16 bf16_t;
typedef __attribute__((ext_vector_type(8))) __bf16 bf16x8;
typedef __attribute__((ext_vector_type(4))) float f32x4;

#define TOK 2048      // N*M tokens
#define DMODEL 1024
#define NHEAD 16
#define DKH 64

// ---------------- fp32 -> bf16 batched convert (weights only) ----------------
struct CvtArgs {
  const float* src[4];
  bf16_t* dst[4];
};

__global__ __launch_bounds__(256) void cvt_kernel(CvtArgs a) {
  int arr = blockIdx.y;
  int i = (blockIdx.x * 256 + threadIdx.x) * 8;
  const float* s = a.src[arr];
  bf16_t* d = a.dst[arr];
  f32x4 x0 = *(const f32x4*)(s + i);
  f32x4 x1 = *(const f32x4*)(s + i + 4);
  bf16x8 o;
  o[0] = (bf16_t)x0[0]; o[1] = (bf16_t)x0[1]; o[2] = (bf16_t)x0[2]; o[3] = (bf16_t)x0[3];
  o[4] = (bf16_t)x1[0]; o[5] = (bf16_t)x1[1]; o[6] = (bf16_t)x1[2]; o[7] = (bf16_t)x1[3];
  *(bf16x8*)(d + i) = o;
}

// =============== fused QKV projection + channel attention ===============
// Block = (64 tokens, 1 head). For z in {q,k,v}: 64x64x1024 GEMM (A fp32
// converted in staging, W bf16), results parked in LDS. Then per-token
// channel softmax + PV, ctx written to global bf16.
struct QkvaArgs {
  const float* X[3];       // query, key, value fp32 [2048][1024]
  const bf16_t* W[3];      // Wq, Wk, Wv bf16 [1024][1024] (row j = output col j)
  const float* bias[3];
  bf16_t* ctx;
};

__global__ __launch_bounds__(256, 3) void qkva_kernel(QkvaArgs g) {
  __shared__ alignas(16) bf16_t As[64][72];
  __shared__ alignas(16) bf16_t Bs[64][72];
  __shared__ alignas(16) bf16_t qS[64][72];
  __shared__ uint32_t kvS[64][66];   // {k:lo16, v:hi16} bf16-packed

  const int tid = threadIdx.x;
  const int wv = tid >> 6, lane = tid & 63;

  // bijective XCD swizzle; chunk of 64 consecutive nid = 4 bm x 16 h
  const int oldid = blockIdx.x + gridDim.x * blockIdx.y;   // 0..511
  const int nid = (oldid & 7) * 64 + (oldid >> 3);
  const int h = nid & 15;
  const int bm = (nid >> 4) * 64;
  const int bn = h * 64;

  const int wr = (wv >> 1) * 32, wc = (wv & 1) * 32;
  const int lm = lane & 15, lk = (lane >> 4) * 8;
  const int cr4 = (lane >> 4) * 4;
  const int trow = tid >> 2, tcol = (tid & 3) * 16;

  for (int z = 0; z < 3; ++z) {
    const float* A = g.X[z] + (size_t)(bm + trow) * DMODEL + tcol;
    const bf16_t* Wp = g.W[z] + (size_t)(bn + trow) * DMODEL + tcol;
    f32x4 acc[2][2] = {};

    // prologue: stage tile 0 (A converts fp32->bf16 in regs)
    {
      f32x4 a0 = *(const f32x4*)(A);
      f32x4 a1 = *(const f32x4*)(A + 4);
      f32x4 a2 = *(const f32x4*)(A + 8);
      f32x4 a3 = *(const f32x4*)(A + 12);
      bf16x8 w0 = *(const bf16x8*)(Wp);
      bf16x8 w1 = *(const bf16x8*)(Wp + 8);
      bf16x8 c0, c1;
#pragma unroll
      for (int e = 0; e < 4; ++e) {
        c0[e] = (bf16_t)a0[e]; c0[e + 4] = (bf16_t)a1[e];
        c1[e] = (bf16_t)a2[e]; c1[e + 4] = (bf16_t)a3[e];
      }
      *(bf16x8*)&As[trow][tcol] = c0;
      *(bf16x8*)&As[trow][tcol + 8] = c1;
      *(bf16x8*)&Bs[trow][tcol] = w0;
      *(bf16x8*)&Bs[trow][tcol + 8] = w1;
    }
    __syncthreads();

    for (int t = 0; t < 16; ++t) {
      f32x4 na0, na1, na2, na3; bf16x8 nw0, nw1;
      const bool more = t < 15;
      if (more) {
        const float* ap = A + (t + 1) * 64;
        const bf16_t* wp2 = Wp + (t + 1) * 64;
        na0 = *(const f32x4*)(ap);     na1 = *(const f32x4*)(ap + 4);
        na2 = *(const f32x4*)(ap + 8); na3 = *(const f32x4*)(ap + 12);
        nw0 = *(const bf16x8*)(wp2);   nw1 = *(const bf16x8*)(wp2 + 8);
      }

      bf16x8 fa[2][2], fb[2][2];
#pragma unroll
      for (int kk = 0; kk < 2; ++kk)
#pragma unroll
        for (int i = 0; i < 2; ++i) {
          fa[kk][i] = *(const bf16x8*)&As[wr + i * 16 + lm][kk * 32 + lk];
          fb[kk][i] = *(const bf16x8*)&Bs[wc + i * 16 + lm][kk * 32 + lk];
        }
      asm volatile("s_waitcnt lgkmcnt(0)" ::: "memory");
      __builtin_amdgcn_sched_barrier(0);
      __builtin_amdgcn_s_barrier();

#pragma unroll
      for (int kk = 0; kk < 2; ++kk)
#pragma unroll
        for (int i = 0; i < 2; ++i)
#pragma unroll
          for (int j = 0; j < 2; ++j)
            acc[i][j] = __builtin_amdgcn_mfma_f32_16x16x32_bf16(fa[kk][i], fb[kk][j], acc[i][j], 0, 0, 0);

      if (more) {
        bf16x8 c0, c1;
#pragma unroll
        for (int e = 0; e < 4; ++e) {
          c0[e] = (bf16_t)na0[e]; c0[e + 4] = (bf16_t)na1[e];
          c1[e] = (bf16_t)na2[e]; c1[e + 4] = (bf16_t)na3[e];
        }
        *(bf16x8*)&As[trow][tcol] = c0;
        *(bf16x8*)&As[trow][tcol + 8] = c1;
        *(bf16x8*)&Bs[trow][tcol] = nw0;
        *(bf16x8*)&Bs[trow][tcol + 8] = nw1;
        asm volatile("s_waitcnt lgkmcnt(0)" ::: "memory");
        __builtin_amdgcn_sched_barrier(0);
        __builtin_amdgcn_s_barrier();
      }
    }

    // epilogue: add bias, park result in LDS attn buffers
    const float* bz = g.bias[z];
#pragma unroll
    for (int i = 0; i < 2; ++i)
#pragma unroll
      for (int j = 0; j < 2; ++j) {
        const int col = wc + j * 16 + lm;
        const float bvv = bz[bn + col];
#pragma unroll
        for (int r = 0; r < 4; ++r) {
          const int row = wr + i * 16 + cr4 + r;
          const float val = acc[i][j][r] + bvv;
          const bf16_t hv = (bf16_t)val;
          if (z == 0) {
            qS[row][col] = hv;
          } else {
            uint16_t* p = (uint16_t*)&kvS[row][col];
            p[z - 1] = __builtin_bit_cast(uint16_t, hv);   // z=1 -> k(lo), z=2 -> v(hi)
          }
        }
      }
  }
  __syncthreads();

  // ---- attention phase: wave wv handles tokens [wv*16, wv*16+16), lane = d ----
  const float sc = 0.125f * 1.44269504088896341f;   // (1/sqrt(64)) * log2(e)
  bf16_t* ctxp = g.ctx + (size_t)bm * DMODEL + bn + lane;
#pragma unroll 2
  for (int tt = 0; tt < 16; ++tt) {
    const int tok = wv * 16 + tt;
    const float a = (float)qS[tok][lane] * sc;
    float sum = 0.f, accv = 0.f;
#pragma unroll 16
    for (int j = 0; j < 64; ++j) {
      const uint32_t kv = kvS[tok][j];
      const float kf = __builtin_bit_cast(float, kv << 16);
      const float vf = __builtin_bit_cast(float, kv & 0xffff0000u);
      const float e = __builtin_amdgcn_exp2f(a * kf);
      sum += e;
      accv = fmaf(e, vf, accv);
    }
    ctxp[(size_t)tok * DMODEL] = (bf16_t)(accv * __builtin_amdgcn_rcpf(sum));
  }
}

// ---------------- bf16 MFMA GEMM (out-projection): C = A@W.T + bias ----------------
#define BM 64
#define BN 64
#define LDK 72

template <typename CT>
__global__ __launch_bounds__(256) void gemm_bt(const bf16_t* __restrict__ A,
                                               const bf16_t* __restrict__ W,
                                               const float* __restrict__ bias,
                                               CT* __restrict__ C, int M, int N, int K) {
  const int nwg = gridDim.x * gridDim.y;
  const int oldid = blockIdx.x + gridDim.x * blockIdx.y;
  const int cpx = nwg >> 3;
  const int nid = (oldid & 7) * cpx + (oldid >> 3);
  const int bm = (nid % gridDim.x) * BM;
  const int bn = (nid / gridDim.x) * BN;

  __shared__ alignas(16) bf16_t As[BM][LDK];
  __shared__ alignas(16) bf16_t Bs[BN][LDK];

  const int tid = threadIdx.x;
  const int wv = tid >> 6, lane = tid & 63;
  const int wr = (wv >> 1) * 32, wc = (wv & 1) * 32;
  const int lm = lane & 15;
  const int lk = (lane >> 4) * 8;
  const int trow = tid >> 2;
  const int tcol = (tid & 3) * 16;

  const bf16_t* arow = A + (size_t)(bm + trow) * K + tcol;
  const bf16_t* wrow = W + (size_t)(bn + trow) * K + tcol;

  f32x4 acc[2][2] = {};

  {
    bf16x8 a0 = *(const bf16x8*)(arow);
    bf16x8 a1 = *(const bf16x8*)(arow + 8);
    bf16x8 w0 = *(const bf16x8*)(wrow);
    bf16x8 w1 = *(const bf16x8*)(wrow + 8);
    *(bf16x8*)&As[trow][tcol] = a0;
    *(bf16x8*)&As[trow][tcol + 8] = a1;
    *(bf16x8*)&Bs[trow][tcol] = w0;
    *(bf16x8*)&Bs[trow][tcol + 8] = w1;
  }
  __syncthreads();

  const int nt = K / 64;
  for (int t = 0; t < nt; ++t) {
    bf16x8 na0, na1, nw0, nw1;
    const bool more = (t + 1) < nt;
    if (more) {
      const bf16_t* ap = arow + (size_t)(t + 1) * 64;
      const bf16_t* wp = wrow + (size_t)(t + 1) * 64;
      na0 = *(const bf16x8*)(ap);
      na1 = *(const bf16x8*)(ap + 8);
      nw0 = *(const bf16x8*)(wp);
      nw1 = *(const bf16x8*)(wp + 8);
    }

    bf16x8 fa[2][2], fb[2][2];
#pragma unroll
    for (int kk = 0; kk < 2; ++kk)
#pragma unroll
      for (int i = 0; i < 2; ++i) {
        fa[kk][i] = *(const bf16x8*)&As[wr + i * 16 + lm][kk * 32 + lk];
        fb[kk][i] = *(const bf16x8*)&Bs[wc + i * 16 + lm][kk * 32 + lk];
      }
    asm volatile("s_waitcnt lgkmcnt(0)" ::: "memory");
    __builtin_amdgcn_sched_barrier(0);
    __builtin_amdgcn_s_barrier();

#pragma unroll
    for (int kk = 0; kk < 2; ++kk)
#pragma unroll
      for (int i = 0; i < 2; ++i)
#pragma unroll
        for (int j = 0; j < 2; ++j)
          acc[i][j] = __builtin_amdgcn_mfma_f32_16x16x32_bf16(fa[kk][i], fb[kk][j], acc[i][j], 0, 0, 0);

    if (more) {
      *(bf16x8*)&As[trow][tcol] = na0;
      *(bf16x8*)&As[trow][tcol + 8] = na1;
      *(bf16x8*)&Bs[trow][tcol] = nw0;
      *(bf16x8*)&Bs[trow][tcol + 8] = nw1;
      asm volatile("s_waitcnt lgkmcnt(0)" ::: "memory");
      __builtin_amdgcn_sched_barrier(0);
      __builtin_amdgcn_s_barrier();
    }
  }

  const int cr4 = (lane >> 4) * 4;
#pragma unroll
  for (int i = 0; i < 2; ++i)
#pragma unroll
    for (int j = 0; j < 2; ++j) {
      int col = bn + wc + j * 16 + lm;
      float bvv = bias[col];
#pragma unroll
      for (int r = 0; r < 4; ++r) {
        int row = bm + wr + i * 16 + cr4 + r;
        C[(size_t)row * N + col] = (CT)(acc[i][j][r] + bvv);
      }
    }
}

// ---------------- launch ----------------
extern "C" void kernel_launch(void* const* d_in, const int* in_sizes, int n_in,
                              void* d_out, int out_size, void* d_ws, size_t ws_size,
                              hipStream_t stream) {
  const float* query = (const float*)d_in[0];
  const float* key   = (const float*)d_in[1];
  const float* value = (const float*)d_in[2];
  const float* Wq = (const float*)d_in[3];
  const float* bq = (const float*)d_in[4];
  const float* Wk = (const float*)d_in[5];
  const float* bk = (const float*)d_in[6];
  const float* Wv = (const float*)d_in[7];
  const float* bv = (const float*)d_in[8];
  const float* Wo = (const float*)d_in[9];
  const float* bo = (const float*)d_in[10];
  float* out = (float*)d_out;

  const size_t XE = (size_t)TOK * DMODEL;
  const size_t WE = (size_t)DMODEL * DMODEL;

  char* ws = (char*)d_ws;
  size_t off = 0;
  bf16_t* wb[4];
  for (int i = 0; i < 4; ++i) { wb[i] = (bf16_t*)(ws + off); off += WE * 2; }
  bf16_t* ctxb = (bf16_t*)(ws + off); off += XE * 2;

  // 1) convert weights to bf16
  CvtArgs ca;
  ca.src[0] = Wq; ca.src[1] = Wk; ca.src[2] = Wv; ca.src[3] = Wo;
  ca.dst[0] = wb[0]; ca.dst[1] = wb[1]; ca.dst[2] = wb[2]; ca.dst[3] = wb[3];
  cvt_kernel<<<dim3((unsigned)(WE / (256 * 8)), 4), 256, 0, stream>>>(ca);

  // 2) fused QKV projection + channel attention: grid 32x16 = 512 blocks
  QkvaArgs qa;
  qa.X[0] = query; qa.X[1] = key; qa.X[2] = value;
  qa.W[0] = wb[0]; qa.W[1] = wb[1]; qa.W[2] = wb[2];
  qa.bias[0] = bq; qa.bias[1] = bk; qa.bias[2] = bv;
  qa.ctx = ctxb;
  qkva_kernel<<<dim3(TOK / 64, NHEAD), 256, 0, stream>>>(qa);

  // 3) output projection -> fp32 out: grid 32x16 = 512 blocks
  gemm_bt<float><<<dim3(TOK / BM, DMODEL / BN), 256, 0, stream>>>(
      ctxb, wb[3], bo, out, TOK, DMODEL, DMODEL);
}